// Round 17
// baseline (928.539 us; speedup 1.0000x reference)
//
#include <hip/hip_runtime.h>

#define N_NODES 100000
#define N_EDGES 1600000
#define IN_F 128
#define HID_F 64
#define OUT_F 40
#define N_STEPS 10

static constexpr float DT = 0.1f;
static constexpr float ONE_MINUS_DT = 0.9f;
// SIGMA * sqrt(DT) = 0.01 * sqrt(0.1)
static constexpr float C_NOISE = 0.0031622776601683794f;

typedef unsigned short bf16_t;
typedef unsigned char fp8_t;
typedef __attribute__((ext_vector_type(8))) short bf16x8;  // MFMA A/B frag (4 VGPR)
typedef __attribute__((ext_vector_type(4))) float f32x4;   // MFMA C/D frag / NT loads
typedef __attribute__((ext_vector_type(2))) float f32x2;

// f32 -> bf16 round-to-nearest-even (finite values only)
static __device__ __forceinline__ bf16_t f2bf(float f) {
    union { float f; unsigned u; } v; v.f = f;
    unsigned r = v.u + 0x7fffu + ((v.u >> 16) & 1u);
    return (bf16_t)(r >> 16);
}
// packed f32x2 -> bf16x2 (RNE) — single HW instr on gfx950
static __device__ __forceinline__ unsigned cvt_pk_bf16(float lo, float hi) {
    unsigned r;
    asm("v_cvt_pk_bf16_f32 %0, %1, %2" : "=v"(r) : "v"(lo), "v"(hi));
    return r;
}
// f32 -> fp8 e4m3 (OCP on gfx950), single value via HW pack
static __device__ __forceinline__ fp8_t f32_to_fp8(float v) {
    int r = __builtin_amdgcn_cvt_pk_fp8_f32(v, v, 0, false);
    return (fp8_t)(r & 0xff);
}
// 2 fp8 (word-select within dword; must be literal) -> 2 f32, HW unpack
template <bool HI>
static __device__ __forceinline__ f32x2 fp8x2_to_f32(unsigned w) {
    return __builtin_amdgcn_cvt_pk_f32_fp8((int)w, HI);
}

// ---------------- W[K x NCOL] f32 -> Wt[NCOL x K] bf16 (tiny, once) ----------------
__global__ __launch_bounds__(256) void transpose_w_kernel(const float* __restrict__ W,
                                                          bf16_t* __restrict__ Wt,
                                                          int K, int NCOL) {
    int i = blockIdx.x * 256 + threadIdx.x;
    if (i < K * NCOL) {
        int k = i / NCOL, c = i - k * NCOL;
        Wt[c * K + k] = f2bf(W[i]);
    }
}

// ---------------- degree histograms (int) ----------------
__global__ __launch_bounds__(256) void deg_kernel(const int* __restrict__ src,
                                                  const int* __restrict__ dst,
                                                  int* __restrict__ deg_out,
                                                  int* __restrict__ deg_in) {
    int i = blockIdx.x * 256 + threadIdx.x;
    if (i < N_EDGES) {
        atomicAdd(&deg_out[src[i]], 1);
        atomicAdd(&deg_in[dst[i]], 1);
    }
}

// ---------------- per-node scale factors ----------------
__global__ __launch_bounds__(256) void scale_kernel(const int* __restrict__ deg_out,
                                                    const int* __restrict__ deg_in,
                                                    float* __restrict__ a,
                                                    float* __restrict__ b) {
    int i = blockIdx.x * 256 + threadIdx.x;
    if (i < N_NODES) {
        a[i] = rsqrtf((float)max(deg_out[i], 1));
        b[i] = rsqrtf((float)max(deg_in[i], 1));
    }
}

// ---------------- 3-kernel exclusive scan of deg_in -> row_ptr ----------------
__global__ __launch_bounds__(256) void scan_blocksum_kernel(const int* __restrict__ deg,
                                                            int* __restrict__ blocksum) {
    __shared__ int buf[256];
    int i = blockIdx.x * 256 + threadIdx.x;
    buf[threadIdx.x] = (i < N_NODES) ? deg[i] : 0;
    __syncthreads();
    for (int off = 128; off > 0; off >>= 1) {
        if (threadIdx.x < off) buf[threadIdx.x] += buf[threadIdx.x + off];
        __syncthreads();
    }
    if (threadIdx.x == 0) blocksum[blockIdx.x] = buf[0];
}

__global__ __launch_bounds__(512) void scan_top_kernel(const int* __restrict__ blocksum,
                                                       int* __restrict__ blockpfx,
                                                       int nblocks) {
    __shared__ int buf[512];
    int v = (threadIdx.x < nblocks) ? blocksum[threadIdx.x] : 0;
    buf[threadIdx.x] = v;
    __syncthreads();
    for (int off = 1; off < 512; off <<= 1) {
        int t = (threadIdx.x >= off) ? buf[threadIdx.x - off] : 0;
        __syncthreads();
        buf[threadIdx.x] += t;
        __syncthreads();
    }
    if (threadIdx.x < nblocks) blockpfx[threadIdx.x] = buf[threadIdx.x] - v;
}

__global__ __launch_bounds__(256) void scan_final_kernel(const int* __restrict__ deg,
                                                         const int* __restrict__ blockpfx,
                                                         int* __restrict__ row_ptr,
                                                         int* __restrict__ cursor) {
    __shared__ int buf[256];
    int i = blockIdx.x * 256 + threadIdx.x;
    int v = (i < N_NODES) ? deg[i] : 0;
    buf[threadIdx.x] = v;
    __syncthreads();
    for (int off = 1; off < 256; off <<= 1) {
        int t = (threadIdx.x >= off) ? buf[threadIdx.x - off] : 0;
        __syncthreads();
        buf[threadIdx.x] += t;
        __syncthreads();
    }
    int excl = blockpfx[blockIdx.x] + buf[threadIdx.x] - v;
    if (i < N_NODES) {
        row_ptr[i] = excl;
        cursor[i] = excl;
    }
    if (blockIdx.x == gridDim.x - 1 && threadIdx.x == 255)
        row_ptr[N_NODES] = blockpfx[blockIdx.x] + buf[255];
}

// ---------------- CSR fill: bucket edges by dst ----------------
__global__ __launch_bounds__(256) void fill_kernel(const int* __restrict__ src,
                                                   const int* __restrict__ dst,
                                                   int* __restrict__ cursor,
                                                   int* __restrict__ src_sorted) {
    int e = blockIdx.x * 256 + threadIdx.x;
    if (e < N_EDGES) {
        int pos = atomicAdd(&cursor[dst[e]], 1);
        src_sorted[pos] = src[e];
    }
}

// ---------------- MFMA row GEMM: Y[r,0..64) = (A_f32[r,K] @ W[K,64]) * scale? ----
// 256 threads = 4 waves; wave = 32 rows x 64 cols via 16x16x32 bf16 MFMA.
// B-frags: one bf16x8 load each from pre-transposed Wt[col][k] in global (L2-hot).
// A-frags: f32 loads converted in-register via v_cvt_pk_bf16_f32.
// OUT_FP8: NON-TEMPORAL fp8 stores — m is next consumed by a DIFFERENT XCD's
// gather; pushing lines to Infinity Cache avoids cross-XCD dirty-line service.
template <int K, bool SCALE, bool OUT_FP8, bool OUT_F32>
__global__ __launch_bounds__(256) void mfma_mm_kernel(const float* __restrict__ A,
                                                      const bf16_t* __restrict__ Wt,
                                                      const float* __restrict__ scale,
                                                      fp8_t* __restrict__ Y8,
                                                      float* __restrict__ Yf) {
    const int lane = threadIdx.x & 63;
    const int wid = threadIdx.x >> 6;
    const int g = lane >> 4;   // 0..3
    const int c = lane & 15;   // 0..15
    const int rbase = blockIdx.x * 128 + wid * 32;
    if (rbase >= N_NODES) return;

    constexpr int KS = K / 32;
    union frag_u { unsigned u[4]; bf16x8 v; };

    bf16x8 bfrag[4][KS];
#pragma unroll
    for (int ct = 0; ct < 4; ct++)
#pragma unroll
        for (int ks = 0; ks < KS; ks++)
            bfrag[ct][ks] = *reinterpret_cast<const bf16x8*>(
                Wt + (size_t)(ct * 16 + c) * K + ks * 32 + g * 8);

#pragma unroll
    for (int rt = 0; rt < 2; rt++) {
        const int r0 = rbase + rt * 16;

        bf16x8 afrag[KS];
#pragma unroll
        for (int ks = 0; ks < KS; ks++) {
            const float* ap = A + (size_t)(r0 + c) * K + ks * 32 + g * 8;
            float4 a0 = *reinterpret_cast<const float4*>(ap);
            float4 a1 = *reinterpret_cast<const float4*>(ap + 4);
            frag_u f;
            f.u[0] = cvt_pk_bf16(a0.x, a0.y);
            f.u[1] = cvt_pk_bf16(a0.z, a0.w);
            f.u[2] = cvt_pk_bf16(a1.x, a1.y);
            f.u[3] = cvt_pk_bf16(a1.z, a1.w);
            afrag[ks] = f.v;
        }

        float sc[4];
        if (SCALE) {
#pragma unroll
            for (int i = 0; i < 4; i++) sc[i] = scale[r0 + g * 4 + i];
        }

#pragma unroll
        for (int ct = 0; ct < 4; ct++) {
            f32x4 acc = {0.f, 0.f, 0.f, 0.f};
#pragma unroll
            for (int ks = 0; ks < KS; ks++)
                acc = __builtin_amdgcn_mfma_f32_16x16x32_bf16(afrag[ks], bfrag[ct][ks], acc, 0, 0, 0);
#pragma unroll
            for (int i = 0; i < 4; i++) {
                int row = r0 + g * 4 + i;
                float v = SCALE ? acc[i] * sc[i] : acc[i];
                size_t o = (size_t)row * HID_F + ct * 16 + c;
                if (OUT_FP8) __builtin_nontemporal_store(f32_to_fp8(v), Y8 + o);
                if (OUT_F32) Yf[o] = v;
            }
        }
    }
}

// ---------------- fused gather + Euler-Maruyama update (fp8 m, shfl-free) --------
// One wave per dst node. 8-lane group g independently walks edges e=beg+g, +8...
// src index software-pipelined one iteration ahead (NT load — sequential stream,
// keep L2 for m). Epilogue operands prefetched before the loop; dw non-temporal.
__global__ __launch_bounds__(256) void gather_update_kernel(const fp8_t* __restrict__ m,
                                                            const int* __restrict__ row_ptr,
                                                            const int* __restrict__ src_sorted,
                                                            const float* __restrict__ b,
                                                            float* __restrict__ x,
                                                            const float* __restrict__ dw) {
    int d = blockIdx.x * 4 + (threadIdx.x >> 6);
    int lane = threadIdx.x & 63;
    int g = lane >> 3;   // edge-stream 0..7
    int q = lane & 7;    // feature octet: features [q*8, q*8+8)

    int beg = row_ptr[d];
    int end = row_ptr[d + 1];

    // ---- epilogue prefetch (g==0 lanes only): issue loads now, use after loop ----
    f32x4 x0 = {0,0,0,0}, x1 = {0,0,0,0}, w0 = {0,0,0,0}, w1 = {0,0,0,0};
    float bd = 0.f;
    size_t o = (size_t)d * HID_F + q * 8;
    if (g == 0) {
        x0 = *reinterpret_cast<const f32x4*>(x + o);
        x1 = *reinterpret_cast<const f32x4*>(x + o + 4);
        w0 = __builtin_nontemporal_load(reinterpret_cast<const f32x4*>(dw + o));
        w1 = __builtin_nontemporal_load(reinterpret_cast<const f32x4*>(dw + o + 4));
        bd = b[d];
    }

    float acc[8];
#pragma unroll
    for (int i = 0; i < 8; i++) acc[i] = 0.f;

    // ---- software-pipelined edge loop: src index loaded one iteration ahead ----
    int e = beg + g;
    int s_next = 0;
    if (e < end) s_next = __builtin_nontemporal_load(src_sorted + e);
    for (; e < end; e += 8) {
        int s = s_next;
        if (e + 8 < end) s_next = __builtin_nontemporal_load(src_sorted + e + 8);
        uint2 mv = *reinterpret_cast<const uint2*>(m + (size_t)s * HID_F + q * 8);
        f32x2 p0 = fp8x2_to_f32<false>(mv.x);
        f32x2 p1 = fp8x2_to_f32<true>(mv.x);
        f32x2 p2 = fp8x2_to_f32<false>(mv.y);
        f32x2 p3 = fp8x2_to_f32<true>(mv.y);
        acc[0] += p0.x; acc[1] += p0.y;
        acc[2] += p1.x; acc[3] += p1.y;
        acc[4] += p2.x; acc[5] += p2.y;
        acc[6] += p3.x; acc[7] += p3.y;
    }

#pragma unroll
    for (int i = 0; i < 8; i++) {
        acc[i] += __shfl_xor(acc[i], 8);
        acc[i] += __shfl_xor(acc[i], 16);
        acc[i] += __shfl_xor(acc[i], 32);
    }

    if (g == 0) {
        float s = DT * bd;
        f32x4 r0, r1;
        r0.x = ONE_MINUS_DT * x0.x + s * acc[0] + C_NOISE * w0.x;
        r0.y = ONE_MINUS_DT * x0.y + s * acc[1] + C_NOISE * w0.y;
        r0.z = ONE_MINUS_DT * x0.z + s * acc[2] + C_NOISE * w0.z;
        r0.w = ONE_MINUS_DT * x0.w + s * acc[3] + C_NOISE * w0.w;
        r1.x = ONE_MINUS_DT * x1.x + s * acc[4] + C_NOISE * w1.x;
        r1.y = ONE_MINUS_DT * x1.y + s * acc[5] + C_NOISE * w1.y;
        r1.z = ONE_MINUS_DT * x1.z + s * acc[6] + C_NOISE * w1.z;
        r1.w = ONE_MINUS_DT * x1.w + s * acc[7] + C_NOISE * w1.w;
        *reinterpret_cast<f32x4*>(x + o) = r0;
        *reinterpret_cast<f32x4*>(x + o + 4) = r1;
    }
}

// ---------------- out projection (f32 regw): out[n,40] = x[n,64] @ W_out[64,40] ----
template <int K, int NCOL, int RPW>
__global__ __launch_bounds__(256) void regw_mm_kernel(const float* __restrict__ A,
                                                      const float* __restrict__ W,
                                                      float* __restrict__ Y,
                                                      int nwaves) {
    int lane = threadIdx.x & 63;
    int wid = __builtin_amdgcn_readfirstlane((blockIdx.x * 256 + threadIdx.x) >> 6);
    if (wid >= nwaves) return;

    float wreg[K];
#pragma unroll
    for (int k = 0; k < K; k++)
        wreg[k] = (lane < NCOL) ? W[k * NCOL + lane] : 0.0f;

    int r0 = wid * RPW;
#pragma unroll 1
    for (int rr = 0; rr < RPW; rr += 4) {
        int r = r0 + rr;
        const float* a0 = A + (size_t)(r + 0) * K;
        const float* a1 = A + (size_t)(r + 1) * K;
        const float* a2 = A + (size_t)(r + 2) * K;
        const float* a3 = A + (size_t)(r + 3) * K;
        float acc0 = 0.f, acc1 = 0.f, acc2 = 0.f, acc3 = 0.f;
#pragma unroll
        for (int k = 0; k < K; k++) {
            float w = wreg[k];
            acc0 = fmaf(a0[k], w, acc0);
            acc1 = fmaf(a1[k], w, acc1);
            acc2 = fmaf(a2[k], w, acc2);
            acc3 = fmaf(a3[k], w, acc3);
        }
        if (lane < NCOL) {
            Y[(size_t)(r + 0) * NCOL + lane] = acc0;
            Y[(size_t)(r + 1) * NCOL + lane] = acc1;
            Y[(size_t)(r + 2) * NCOL + lane] = acc2;
            Y[(size_t)(r + 3) * NCOL + lane] = acc3;
        }
    }
}

extern "C" void kernel_launch(void* const* d_in, const int* in_sizes, int n_in,
                              void* d_out, int out_size, void* d_ws, size_t ws_size,
                              hipStream_t stream) {
    const float* h     = (const float*)d_in[0];
    const float* W_in  = (const float*)d_in[1];
    const float* W_msg = (const float*)d_in[2];
    const float* W_out = (const float*)d_in[3];
    const float* dW    = (const float*)d_in[4];
    const int*   src   = (const int*)d_in[5];
    const int*   dst   = (const int*)d_in[6];
    float* out = (float*)d_out;

    const size_t NH = (size_t)N_NODES * HID_F;  // 6.4M
    const int NBLK = (N_NODES + 255) / 256;     // 391

    float*  x       = (float*)d_ws;                          // 6.4M f32 (25.6 MB)
    fp8_t*  m       = (fp8_t*)(x + NH);                      // 6.4M fp8 (6.4 MB)
    bf16_t* Win_t   = (bf16_t*)(m + NH);                     // 8192 bf16 (64 x 128)
    bf16_t* Wmsg_t  = Win_t + IN_F * HID_F;                  // 4096 bf16 (64 x 64)
    float*  a       = (float*)(Wmsg_t + HID_F * HID_F);      // 100K f
    float*  b       = a + N_NODES;                           // 100K f
    int* deg_out_i  = (int*)(b + N_NODES);                   // 100K i
    int* deg_in_i   = deg_out_i + N_NODES;                   // 100K i
    int* row_ptr    = deg_in_i + N_NODES;                    // 100K+1 i
    int* cursor     = row_ptr + N_NODES + 1;                 // 100K+1 i
    int* blocksum   = cursor + N_NODES + 1;                  // 391 i
    int* blockpfx   = blocksum + 512;                        // 391 i
    int* src_sorted = blockpfx + 512;                        // 1.6M i

    // ---- one-time: transposed bf16 weights ----
    transpose_w_kernel<<<dim3((IN_F * HID_F + 255) / 256), 256, 0, stream>>>(
        W_in, Win_t, IN_F, HID_F);
    transpose_w_kernel<<<dim3((HID_F * HID_F + 255) / 256), 256, 0, stream>>>(
        W_msg, Wmsg_t, HID_F, HID_F);

    // ---- one-time: degrees, scales, CSR ----
    (void)hipMemsetAsync(deg_out_i, 0, 2 * N_NODES * sizeof(int), stream);
    {
        dim3 ge((N_EDGES + 255) / 256);
        deg_kernel<<<ge, 256, 0, stream>>>(src, dst, deg_out_i, deg_in_i);
        scale_kernel<<<dim3(NBLK), 256, 0, stream>>>(deg_out_i, deg_in_i, a, b);
        scan_blocksum_kernel<<<dim3(NBLK), 256, 0, stream>>>(deg_in_i, blocksum);
        scan_top_kernel<<<1, 512, 0, stream>>>(blocksum, blockpfx, NBLK);
        scan_final_kernel<<<dim3(NBLK), 256, 0, stream>>>(deg_in_i, blockpfx, row_ptr, cursor);
        fill_kernel<<<ge, 256, 0, stream>>>(src, dst, cursor, src_sorted);
    }

    const dim3 g_mfma((N_NODES + 127) / 128);  // 782

    // ---- x = h @ W_in (f32 out) ----
    mfma_mm_kernel<IN_F, false, false, true><<<g_mfma, 256, 0, stream>>>(
        h, Win_t, nullptr, nullptr, x);

    // ---- 10 Euler-Maruyama steps ----
    const dim3 g_gather(N_NODES / 4);  // 25000
    for (int k = 0; k < N_STEPS; k++) {
        // m = fp8( a * (x @ W_msg) )  — NT stores straight to Infinity Cache
        mfma_mm_kernel<HID_F, true, true, false><<<g_mfma, 256, 0, stream>>>(
            x, Wmsg_t, a, m, nullptr);
        // x = 0.9 x + 0.1 b * gather(m) + C_NOISE dW_k
        gather_update_kernel<<<g_gather, 256, 0, stream>>>(
            m, row_ptr, src_sorted, b, x, dW + (size_t)k * NH);
    }

    // ---- out = x @ W_out ----
    {
        const int nwaves = N_NODES / 8;  // 12500
        regw_mm_kernel<HID_F, OUT_F, 8><<<dim3((nwaves + 3) / 4), 256, 0, stream>>>(
            x, W_out, out, nwaves);
    }
}

// Round 18
// 906.646 us; speedup vs baseline: 1.0241x; 1.0241x over previous
//
#include <hip/hip_runtime.h>

#define N_NODES 100000
#define N_EDGES 1600000
#define IN_F 128
#define HID_F 64
#define OUT_F 40
#define N_STEPS 10

static constexpr float DT = 0.1f;
static constexpr float ONE_MINUS_DT = 0.9f;
// SIGMA * sqrt(DT) = 0.01 * sqrt(0.1)
static constexpr float C_NOISE = 0.0031622776601683794f;

typedef unsigned short bf16_t;
typedef unsigned char fp8_t;
typedef __attribute__((ext_vector_type(8))) short bf16x8;  // MFMA A/B frag (4 VGPR)
typedef __attribute__((ext_vector_type(4))) float f32x4;   // MFMA C/D frag / NT loads
typedef __attribute__((ext_vector_type(2))) float f32x2;

// f32 -> bf16 round-to-nearest-even (finite values only)
static __device__ __forceinline__ bf16_t f2bf(float f) {
    union { float f; unsigned u; } v; v.f = f;
    unsigned r = v.u + 0x7fffu + ((v.u >> 16) & 1u);
    return (bf16_t)(r >> 16);
}
// packed f32x2 -> bf16x2 (RNE) — single HW instr on gfx950
static __device__ __forceinline__ unsigned cvt_pk_bf16(float lo, float hi) {
    unsigned r;
    asm("v_cvt_pk_bf16_f32 %0, %1, %2" : "=v"(r) : "v"(lo), "v"(hi));
    return r;
}
// f32 -> fp8 e4m3 (OCP on gfx950), single value via HW pack
static __device__ __forceinline__ fp8_t f32_to_fp8(float v) {
    int r = __builtin_amdgcn_cvt_pk_fp8_f32(v, v, 0, false);
    return (fp8_t)(r & 0xff);
}
// 2 fp8 (word-select within dword; must be literal) -> 2 f32, HW unpack
template <bool HI>
static __device__ __forceinline__ f32x2 fp8x2_to_f32(unsigned w) {
    return __builtin_amdgcn_cvt_pk_f32_fp8((int)w, HI);
}

// ---------------- W[K x NCOL] f32 -> Wt[NCOL x K] bf16 (tiny, once) ----------------
__global__ __launch_bounds__(256) void transpose_w_kernel(const float* __restrict__ W,
                                                          bf16_t* __restrict__ Wt,
                                                          int K, int NCOL) {
    int i = blockIdx.x * 256 + threadIdx.x;
    if (i < K * NCOL) {
        int k = i / NCOL, c = i - k * NCOL;
        Wt[c * K + k] = f2bf(W[i]);
    }
}

// ---------------- degree histograms (int) ----------------
__global__ __launch_bounds__(256) void deg_kernel(const int* __restrict__ src,
                                                  const int* __restrict__ dst,
                                                  int* __restrict__ deg_out,
                                                  int* __restrict__ deg_in) {
    int i = blockIdx.x * 256 + threadIdx.x;
    if (i < N_EDGES) {
        atomicAdd(&deg_out[src[i]], 1);
        atomicAdd(&deg_in[dst[i]], 1);
    }
}

// ---------------- per-node scale factors ----------------
__global__ __launch_bounds__(256) void scale_kernel(const int* __restrict__ deg_out,
                                                    const int* __restrict__ deg_in,
                                                    float* __restrict__ a,
                                                    float* __restrict__ b) {
    int i = blockIdx.x * 256 + threadIdx.x;
    if (i < N_NODES) {
        a[i] = rsqrtf((float)max(deg_out[i], 1));
        b[i] = rsqrtf((float)max(deg_in[i], 1));
    }
}

// ---------------- 3-kernel exclusive scan of deg_in -> row_ptr ----------------
__global__ __launch_bounds__(256) void scan_blocksum_kernel(const int* __restrict__ deg,
                                                            int* __restrict__ blocksum) {
    __shared__ int buf[256];
    int i = blockIdx.x * 256 + threadIdx.x;
    buf[threadIdx.x] = (i < N_NODES) ? deg[i] : 0;
    __syncthreads();
    for (int off = 128; off > 0; off >>= 1) {
        if (threadIdx.x < off) buf[threadIdx.x] += buf[threadIdx.x + off];
        __syncthreads();
    }
    if (threadIdx.x == 0) blocksum[blockIdx.x] = buf[0];
}

__global__ __launch_bounds__(512) void scan_top_kernel(const int* __restrict__ blocksum,
                                                       int* __restrict__ blockpfx,
                                                       int nblocks) {
    __shared__ int buf[512];
    int v = (threadIdx.x < nblocks) ? blocksum[threadIdx.x] : 0;
    buf[threadIdx.x] = v;
    __syncthreads();
    for (int off = 1; off < 512; off <<= 1) {
        int t = (threadIdx.x >= off) ? buf[threadIdx.x - off] : 0;
        __syncthreads();
        buf[threadIdx.x] += t;
        __syncthreads();
    }
    if (threadIdx.x < nblocks) blockpfx[threadIdx.x] = buf[threadIdx.x] - v;
}

__global__ __launch_bounds__(256) void scan_final_kernel(const int* __restrict__ deg,
                                                         const int* __restrict__ blockpfx,
                                                         int* __restrict__ row_ptr,
                                                         int* __restrict__ cursor) {
    __shared__ int buf[256];
    int i = blockIdx.x * 256 + threadIdx.x;
    int v = (i < N_NODES) ? deg[i] : 0;
    buf[threadIdx.x] = v;
    __syncthreads();
    for (int off = 1; off < 256; off <<= 1) {
        int t = (threadIdx.x >= off) ? buf[threadIdx.x - off] : 0;
        __syncthreads();
        buf[threadIdx.x] += t;
        __syncthreads();
    }
    int excl = blockpfx[blockIdx.x] + buf[threadIdx.x] - v;
    if (i < N_NODES) {
        row_ptr[i] = excl;
        cursor[i] = excl;
    }
    if (blockIdx.x == gridDim.x - 1 && threadIdx.x == 255)
        row_ptr[N_NODES] = blockpfx[blockIdx.x] + buf[255];
}

// ---------------- CSR fill: bucket edges by dst ----------------
__global__ __launch_bounds__(256) void fill_kernel(const int* __restrict__ src,
                                                   const int* __restrict__ dst,
                                                   int* __restrict__ cursor,
                                                   int* __restrict__ src_sorted) {
    int e = blockIdx.x * 256 + threadIdx.x;
    if (e < N_EDGES) {
        int pos = atomicAdd(&cursor[dst[e]], 1);
        src_sorted[pos] = src[e];
    }
}

// ---------------- MFMA row GEMM: Y[r,0..64) = (A_f32[r,K] @ W[K,64]) * scale? ----
// 256 threads = 4 waves; wave = 32 rows x 64 cols via 16x16x32 bf16 MFMA.
// B-frags: one bf16x8 load each from pre-transposed Wt[col][k] in global (L2-hot).
// A-frags: f32 loads converted in-register via v_cvt_pk_bf16_f32.
// OUT_FP8: regular (cached) fp8 stores — the writing XCD's L2 then serves
// ~1/8 of next gather's reads locally (NT stores measured -2% in r17).
template <int K, bool SCALE, bool OUT_FP8, bool OUT_F32>
__global__ __launch_bounds__(256) void mfma_mm_kernel(const float* __restrict__ A,
                                                      const bf16_t* __restrict__ Wt,
                                                      const float* __restrict__ scale,
                                                      fp8_t* __restrict__ Y8,
                                                      float* __restrict__ Yf) {
    const int lane = threadIdx.x & 63;
    const int wid = threadIdx.x >> 6;
    const int g = lane >> 4;   // 0..3
    const int c = lane & 15;   // 0..15
    const int rbase = blockIdx.x * 128 + wid * 32;
    if (rbase >= N_NODES) return;

    constexpr int KS = K / 32;
    union frag_u { unsigned u[4]; bf16x8 v; };

    bf16x8 bfrag[4][KS];
#pragma unroll
    for (int ct = 0; ct < 4; ct++)
#pragma unroll
        for (int ks = 0; ks < KS; ks++)
            bfrag[ct][ks] = *reinterpret_cast<const bf16x8*>(
                Wt + (size_t)(ct * 16 + c) * K + ks * 32 + g * 8);

#pragma unroll
    for (int rt = 0; rt < 2; rt++) {
        const int r0 = rbase + rt * 16;

        bf16x8 afrag[KS];
#pragma unroll
        for (int ks = 0; ks < KS; ks++) {
            const float* ap = A + (size_t)(r0 + c) * K + ks * 32 + g * 8;
            float4 a0 = *reinterpret_cast<const float4*>(ap);
            float4 a1 = *reinterpret_cast<const float4*>(ap + 4);
            frag_u f;
            f.u[0] = cvt_pk_bf16(a0.x, a0.y);
            f.u[1] = cvt_pk_bf16(a0.z, a0.w);
            f.u[2] = cvt_pk_bf16(a1.x, a1.y);
            f.u[3] = cvt_pk_bf16(a1.z, a1.w);
            afrag[ks] = f.v;
        }

        float sc[4];
        if (SCALE) {
#pragma unroll
            for (int i = 0; i < 4; i++) sc[i] = scale[r0 + g * 4 + i];
        }

#pragma unroll
        for (int ct = 0; ct < 4; ct++) {
            f32x4 acc = {0.f, 0.f, 0.f, 0.f};
#pragma unroll
            for (int ks = 0; ks < KS; ks++)
                acc = __builtin_amdgcn_mfma_f32_16x16x32_bf16(afrag[ks], bfrag[ct][ks], acc, 0, 0, 0);
#pragma unroll
            for (int i = 0; i < 4; i++) {
                int row = r0 + g * 4 + i;
                float v = SCALE ? acc[i] * sc[i] : acc[i];
                size_t o = (size_t)row * HID_F + ct * 16 + c;
                if (OUT_FP8) Y8[o] = f32_to_fp8(v);
                if (OUT_F32) Yf[o] = v;
            }
        }
    }
}

// ---------------- fused gather + Euler-Maruyama update (fp8 m, shfl-free) --------
// One wave per dst node. 8-lane group g independently walks edges e=beg+g, +8...
// All 8 lanes of a group load the same src_sorted[e] (HW broadcast), then each
// lane loads its uint2 (8B = 8 fp8 features at q=lane&7).
// Epilogue operands (x, dw, b) prefetched BEFORE the edge loop so their
// L3/HBM latency hides under the gather; dw uses non-temporal loads (streamed
// once per launch — keep it out of L2/L3 so the m table stays resident).
__global__ __launch_bounds__(256) void gather_update_kernel(const fp8_t* __restrict__ m,
                                                            const int* __restrict__ row_ptr,
                                                            const int* __restrict__ src_sorted,
                                                            const float* __restrict__ b,
                                                            float* __restrict__ x,
                                                            const float* __restrict__ dw) {
    int d = blockIdx.x * 4 + (threadIdx.x >> 6);
    int lane = threadIdx.x & 63;
    int g = lane >> 3;   // edge-stream 0..7
    int q = lane & 7;    // feature octet: features [q*8, q*8+8)

    int beg = row_ptr[d];
    int end = row_ptr[d + 1];

    // ---- epilogue prefetch (g==0 lanes only): issue loads now, use after loop ----
    f32x4 x0 = {0,0,0,0}, x1 = {0,0,0,0}, w0 = {0,0,0,0}, w1 = {0,0,0,0};
    float bd = 0.f;
    size_t o = (size_t)d * HID_F + q * 8;
    if (g == 0) {
        x0 = *reinterpret_cast<const f32x4*>(x + o);
        x1 = *reinterpret_cast<const f32x4*>(x + o + 4);
        w0 = __builtin_nontemporal_load(reinterpret_cast<const f32x4*>(dw + o));
        w1 = __builtin_nontemporal_load(reinterpret_cast<const f32x4*>(dw + o + 4));
        bd = b[d];
    }

    float acc[8];
#pragma unroll
    for (int i = 0; i < 8; i++) acc[i] = 0.f;

#pragma unroll 2
    for (int e = beg + g; e < end; e += 8) {
        int s = src_sorted[e];   // same addr across the 8-lane group -> broadcast
        uint2 mv = *reinterpret_cast<const uint2*>(m + (size_t)s * HID_F + q * 8);
        f32x2 p0 = fp8x2_to_f32<false>(mv.x);
        f32x2 p1 = fp8x2_to_f32<true>(mv.x);
        f32x2 p2 = fp8x2_to_f32<false>(mv.y);
        f32x2 p3 = fp8x2_to_f32<true>(mv.y);
        acc[0] += p0.x; acc[1] += p0.y;
        acc[2] += p1.x; acc[3] += p1.y;
        acc[4] += p2.x; acc[5] += p2.y;
        acc[6] += p3.x; acc[7] += p3.y;
    }

#pragma unroll
    for (int i = 0; i < 8; i++) {
        acc[i] += __shfl_xor(acc[i], 8);
        acc[i] += __shfl_xor(acc[i], 16);
        acc[i] += __shfl_xor(acc[i], 32);
    }

    if (g == 0) {
        float s = DT * bd;
        f32x4 r0, r1;
        r0.x = ONE_MINUS_DT * x0.x + s * acc[0] + C_NOISE * w0.x;
        r0.y = ONE_MINUS_DT * x0.y + s * acc[1] + C_NOISE * w0.y;
        r0.z = ONE_MINUS_DT * x0.z + s * acc[2] + C_NOISE * w0.z;
        r0.w = ONE_MINUS_DT * x0.w + s * acc[3] + C_NOISE * w0.w;
        r1.x = ONE_MINUS_DT * x1.x + s * acc[4] + C_NOISE * w1.x;
        r1.y = ONE_MINUS_DT * x1.y + s * acc[5] + C_NOISE * w1.y;
        r1.z = ONE_MINUS_DT * x1.z + s * acc[6] + C_NOISE * w1.z;
        r1.w = ONE_MINUS_DT * x1.w + s * acc[7] + C_NOISE * w1.w;
        *reinterpret_cast<f32x4*>(x + o) = r0;
        *reinterpret_cast<f32x4*>(x + o + 4) = r1;
    }
}

// ---------------- out projection (f32 regw): out[n,40] = x[n,64] @ W_out[64,40] ----
template <int K, int NCOL, int RPW>
__global__ __launch_bounds__(256) void regw_mm_kernel(const float* __restrict__ A,
                                                      const float* __restrict__ W,
                                                      float* __restrict__ Y,
                                                      int nwaves) {
    int lane = threadIdx.x & 63;
    int wid = __builtin_amdgcn_readfirstlane((blockIdx.x * 256 + threadIdx.x) >> 6);
    if (wid >= nwaves) return;

    float wreg[K];
#pragma unroll
    for (int k = 0; k < K; k++)
        wreg[k] = (lane < NCOL) ? W[k * NCOL + lane] : 0.0f;

    int r0 = wid * RPW;
#pragma unroll 1
    for (int rr = 0; rr < RPW; rr += 4) {
        int r = r0 + rr;
        const float* a0 = A + (size_t)(r + 0) * K;
        const float* a1 = A + (size_t)(r + 1) * K;
        const float* a2 = A + (size_t)(r + 2) * K;
        const float* a3 = A + (size_t)(r + 3) * K;
        float acc0 = 0.f, acc1 = 0.f, acc2 = 0.f, acc3 = 0.f;
#pragma unroll
        for (int k = 0; k < K; k++) {
            float w = wreg[k];
            acc0 = fmaf(a0[k], w, acc0);
            acc1 = fmaf(a1[k], w, acc1);
            acc2 = fmaf(a2[k], w, acc2);
            acc3 = fmaf(a3[k], w, acc3);
        }
        if (lane < NCOL) {
            Y[(size_t)(r + 0) * NCOL + lane] = acc0;
            Y[(size_t)(r + 1) * NCOL + lane] = acc1;
            Y[(size_t)(r + 2) * NCOL + lane] = acc2;
            Y[(size_t)(r + 3) * NCOL + lane] = acc3;
        }
    }
}

extern "C" void kernel_launch(void* const* d_in, const int* in_sizes, int n_in,
                              void* d_out, int out_size, void* d_ws, size_t ws_size,
                              hipStream_t stream) {
    const float* h     = (const float*)d_in[0];
    const float* W_in  = (const float*)d_in[1];
    const float* W_msg = (const float*)d_in[2];
    const float* W_out = (const float*)d_in[3];
    const float* dW    = (const float*)d_in[4];
    const int*   src   = (const int*)d_in[5];
    const int*   dst   = (const int*)d_in[6];
    float* out = (float*)d_out;

    const size_t NH = (size_t)N_NODES * HID_F;  // 6.4M
    const int NBLK = (N_NODES + 255) / 256;     // 391

    float*  x       = (float*)d_ws;                          // 6.4M f32 (25.6 MB)
    fp8_t*  m       = (fp8_t*)(x + NH);                      // 6.4M fp8 (6.4 MB)
    bf16_t* Win_t   = (bf16_t*)(m + NH);                     // 8192 bf16 (64 x 128)
    bf16_t* Wmsg_t  = Win_t + IN_F * HID_F;                  // 4096 bf16 (64 x 64)
    float*  a       = (float*)(Wmsg_t + HID_F * HID_F);      // 100K f
    float*  b       = a + N_NODES;                           // 100K f
    int* deg_out_i  = (int*)(b + N_NODES);                   // 100K i
    int* deg_in_i   = deg_out_i + N_NODES;                   // 100K i
    int* row_ptr    = deg_in_i + N_NODES;                    // 100K+1 i
    int* cursor     = row_ptr + N_NODES + 1;                 // 100K+1 i
    int* blocksum   = cursor + N_NODES + 1;                  // 391 i
    int* blockpfx   = blocksum + 512;                        // 391 i
    int* src_sorted = blockpfx + 512;                        // 1.6M i

    // ---- one-time: transposed bf16 weights ----
    transpose_w_kernel<<<dim3((IN_F * HID_F + 255) / 256), 256, 0, stream>>>(
        W_in, Win_t, IN_F, HID_F);
    transpose_w_kernel<<<dim3((HID_F * HID_F + 255) / 256), 256, 0, stream>>>(
        W_msg, Wmsg_t, HID_F, HID_F);

    // ---- one-time: degrees, scales, CSR ----
    (void)hipMemsetAsync(deg_out_i, 0, 2 * N_NODES * sizeof(int), stream);
    {
        dim3 ge((N_EDGES + 255) / 256);
        deg_kernel<<<ge, 256, 0, stream>>>(src, dst, deg_out_i, deg_in_i);
        scale_kernel<<<dim3(NBLK), 256, 0, stream>>>(deg_out_i, deg_in_i, a, b);
        scan_blocksum_kernel<<<dim3(NBLK), 256, 0, stream>>>(deg_in_i, blocksum);
        scan_top_kernel<<<1, 512, 0, stream>>>(blocksum, blockpfx, NBLK);
        scan_final_kernel<<<dim3(NBLK), 256, 0, stream>>>(deg_in_i, blockpfx, row_ptr, cursor);
        fill_kernel<<<ge, 256, 0, stream>>>(src, dst, cursor, src_sorted);
    }

    const dim3 g_mfma((N_NODES + 127) / 128);  // 782

    // ---- x = h @ W_in (f32 out) ----
    mfma_mm_kernel<IN_F, false, false, true><<<g_mfma, 256, 0, stream>>>(
        h, Win_t, nullptr, nullptr, x);

    // ---- 10 Euler-Maruyama steps ----
    const dim3 g_gather(N_NODES / 4);  // 25000
    for (int k = 0; k < N_STEPS; k++) {
        // m = fp8( a * (x @ W_msg) )
        mfma_mm_kernel<HID_F, true, true, false><<<g_mfma, 256, 0, stream>>>(
            x, Wmsg_t, a, m, nullptr);
        // x = 0.9 x + 0.1 b * gather(m) + C_NOISE dW_k
        gather_update_kernel<<<g_gather, 256, 0, stream>>>(
            m, row_ptr, src_sorted, b, x, dW + (size_t)k * NH);
    }

    // ---- out = x @ W_out ----
    {
        const int nwaves = N_NODES / 8;  // 12500
        regw_mm_kernel<HID_F, OUT_F, 8><<<dim3((nwaves + 3) / 4), 256, 0, stream>>>(
            x, W_out, out, nwaves);
    }
}